// Round 23
// baseline (101.118 us; speedup 1.0000x reference)
//
#include <hip/hip_runtime.h>
#include <hip/hip_bf16.h>

#define BATCH   32768
#define DIM     2048
#define NHEADS  28
#define NCOLS   280
#define LOSS_SCALE (1.0f / (float)(BATCH * NHEADS))

typedef __attribute__((ext_vector_type(8))) short short8;
typedef __attribute__((ext_vector_type(4))) short s4vec;
typedef __attribute__((ext_vector_type(4))) float f32x4;

__device__ __forceinline__ short f2bf(float f) {
    union { __hip_bfloat16 h; short s; } u; u.h = __float2bfloat16(f); return u.s;
}

// ---------------------------------------------------------------------------
// W pre-swizzle, HALF-SPLIT layout: N split 140+140 (heads 0-13 / 14-27).
// Per k-tile kt: 18 frags (nh2*9+nf), each 512 shorts:
//   short idx = kt*9216 + f*512 + lane*8 + j
//   local col lc = nf*16 + (lane&15);  n = nh2*140 + lc  (0 if lc >= 140)
//   d = kt*32 + (lane>>4)*8 + j
// ---------------------------------------------------------------------------
__global__ void mvh_swz(const float* __restrict__ W, short* __restrict__ Wswz) {
    int t = blockIdx.x * 256 + threadIdx.x;      // 73728 threads
    int kt = t / 1152;
    int r  = t - kt * 1152;
    int f  = r >> 6;                             // 0..17
    int l  = r & 63;
    int nh2 = (f >= 9) ? 1 : 0;
    int nf  = f - nh2 * 9;
    int lc  = nf * 16 + (l & 15);
    int n   = nh2 * 140 + lc;
    int d   = kt * 32 + (l >> 4) * 8;
    short8 v;
    #pragma unroll
    for (int j = 0; j < 8; j++) v[j] = 0;
    if (lc < 140) {
        const float* src = W + (size_t)n * DIM + d;
        #pragma unroll
        for (int j = 0; j < 8; j++) v[j] = f2bf(src[j]);
    }
    *(short8*)(Wswz + (size_t)t * 8) = v;
}

// ---------------------------------------------------------------------------
// GEMM + FUSED LOSS, v8 "32-barrier pair": N-split 140/140 per block.
// grid 1024 x 512 thr; block = 64 rows x 140 cols; 8 waves = kph(2) x
// wsub(4, 16 rows); acc 9 x f32x4 = 36 VGPR. Per interval BOTH parities
// compute (kph0 -> tile 2i, kph1 -> tile 2i+1, disjoint LDS) -> ONE barrier
// per 2 k-tiles = 32 barriers (half of every prior variant; the one axis
// never tested). LDS = 4 A-slots (4KB) + 4 B-slots (9.2KB) = 53248.
// Counted vmcnt: per interval tid<64 issues 4 B, else 2 B; +2 A (uniform);
// vmcnt(2) drains all B, keeps the 2 A flying (~1 interval). i=30: no A
// issued -> vmcnt(0) (R19 lesson). XCD pairing: rowblk=((bid>>4)<<3)|(bid&7),
// nh2=(bid>>3)&1 -> pair-mates share bid%8 (same XCD, <=8 dispatch apart)
// so A's second read hits that XCD's L2 -> HBM FETCH ~unchanged.
// T5 setprio around MFMA. Single-pass epilogue: Cl[64][148], 140-col
// contiguous stores, 64x14 logsumexp, one atomicAdd.
// ---------------------------------------------------------------------------
#define ASL(t) (((t) & 3) * 4096)
#define BSL(t) (16384 + ((t) & 3) * 9216)
#define CLP 148

#define SB0() __builtin_amdgcn_sched_barrier(0)
#define BARV2() do { SB0(); asm volatile("s_waitcnt vmcnt(2) lgkmcnt(0)" ::: "memory"); \
    __builtin_amdgcn_s_barrier(); SB0(); } while (0)
#define BARV0() do { SB0(); asm volatile("s_waitcnt vmcnt(0) lgkmcnt(0)" ::: "memory"); \
    __builtin_amdgcn_s_barrier(); SB0(); } while (0)

__global__ __launch_bounds__(512, 4)
void mvh_gemm(const float* __restrict__ hidden, const short* __restrict__ Wswz,
              const float* __restrict__ bias, float* __restrict__ logits,
              const int* __restrict__ labels, float* __restrict__ loss_out) {
    __shared__ __align__(16) char lds[53248];

    const int tid  = threadIdx.x;
    const int lane = tid & 63;
    const int wave = tid >> 6;
    const int kph  = wave >> 2;         // tile-parity owner
    const int wsub = wave & 3;          // 16-row slice
    const int l15 = lane & 15, lhi = lane >> 4;
    // XCD-paired decomposition (bijective): mates (nh2=0/1) share bid%8.
    const int bid = blockIdx.x;
    const int rowblk = ((bid >> 4) << 3) | (bid & 7);
    const int nh2 = (bid >> 3) & 1;
    const int rowbase = rowblk * 64;

    // A staging map: row ar=tid>>3, k-floats [ak4, ak4+4) of one 32-k tile.
    const int ar  = tid >> 3;
    const int ak4 = (tid & 7) * 4;
    const float* gAbase = hidden + (size_t)(rowbase + ar) * DIM + ak4;
    const int awbyte = (ar >> 4) * 1024 + ((ar & 15) + 16 * (ak4 >> 3)) * 16 + (ak4 & 4) * 2;

    f32x4 acc[9];
    #pragma unroll
    for (int n = 0; n < 9; n++) acc[n] = (f32x4)0.0f;

    f32x4 ga, gb;   // two A tiles in flight (even/odd of next pair)

#define LOADA1(reg, t) do { reg = *(const f32x4*)(gAbase + (size_t)(t) * 32); SB0(); } while (0)

#define WRITEA1(aoff, reg) do { \
    s4vec w_; \
    w_[0] = f2bf(reg[0]); w_[1] = f2bf(reg[1]); w_[2] = f2bf(reg[2]); w_[3] = f2bf(reg[3]); \
    *(s4vec*)(lds + (aoff) + awbyte) = w_; \
} while (0)

#define STAGE_B(boff, kt) do { \
    _Pragma("unroll") \
    for (int i_ = 0; i_ < 2; i_++) { \
        if (i_ == 0 || tid < 64) { \
            int g_ = i_ * 512 + tid; \
            const short* gp_ = Wswz + (size_t)(kt) * 9216 + (nh2 * 9 + (g_ >> 6)) * 512 + (g_ & 63) * 8; \
            __builtin_amdgcn_global_load_lds((const __attribute__((address_space(1))) void*)gp_, \
                (__attribute__((address_space(3))) void*)(lds + (boff) + g_ * 16), 16, 0, 0); \
        } \
    } \
    SB0(); \
} while (0)

#define COMPUTE(aoff, boff) do { \
    short8 af_ = *(const short8*)(lds + (aoff) + wsub * 1024 + lane * 16); \
    __builtin_amdgcn_s_setprio(1); \
    _Pragma("unroll") \
    for (int n_ = 0; n_ < 9; n_++) { \
        short8 bf_ = *(const short8*)(lds + (boff) + n_ * 1024 + lane * 16); \
        acc[n_] = __builtin_amdgcn_mfma_f32_16x16x32_bf16(af_, bf_, acc[n_], 0, 0, 0); \
    } \
    __builtin_amdgcn_s_setprio(0); \
} while (0)

    // ---- prologue: B(0),B(1) staged; A(0),A(1) -> LDS; A(2),A(3) -> regs ----
    STAGE_B(BSL(0), 0);
    STAGE_B(BSL(1), 1);
    LOADA1(ga, 0); LOADA1(gb, 1);
    WRITEA1(ASL(0), ga);            // auto-waits A(0)/A(1) regs only
    WRITEA1(ASL(1), gb);
    LOADA1(ga, 2); LOADA1(gb, 3);
    BARV2();                        // drain B(0),B(1); A(2),A(3) keep flying

    // ---- main: 32 intervals, each = 2 tiles, ONE barrier ----
    #pragma unroll 1
    for (int i = 0; i < 32; i++) {
        const int T = i * 2;
        if (i < 31) { STAGE_B(BSL(T + 2), T + 2); STAGE_B(BSL(T + 3), T + 3); }
        if (kph == 0) COMPUTE(ASL(T), BSL(T));
        else          COMPUTE(ASL(T + 1), BSL(T + 1));
        SB0();
        if (i < 31) { WRITEA1(ASL(T + 2), ga); WRITEA1(ASL(T + 3), gb); }
        if (i < 30) { LOADA1(ga, T + 4); LOADA1(gb, T + 5); }
        if (i < 30)      { BARV2(); }   // drain B pair, keep 2 A flying
        else if (i == 30){ BARV0(); }   // no A issued this interval
        // i == 31: epilogue __syncthreads follows
    }

#undef LOADA1
#undef WRITEA1
#undef STAGE_B
#undef COMPUTE

    // ---- fused epilogue v3: single-pass Cl[64][148], bias on read ----
    float* Cl  = (float*)lds;                       // 37888 B
    float* red = (float*)(lds + 38912);
    float lsum = 0.0f;

    __syncthreads();
    if (kph == 1) {
        #pragma unroll
        for (int nf = 0; nf < 9; nf++) {
            int c = nf * 16 + l15;
            #pragma unroll
            for (int r = 0; r < 4; r++)
                Cl[(wsub * 16 + lhi * 4 + r) * CLP + c] = acc[nf][r];
        }
    }
    __syncthreads();
    if (kph == 0) {
        #pragma unroll
        for (int nf = 0; nf < 9; nf++) {
            int c = nf * 16 + l15;
            #pragma unroll
            for (int r = 0; r < 4; r++)
                Cl[(wsub * 16 + lhi * 4 + r) * CLP + c] += acc[nf][r];
        }
    }
    __syncthreads();
    // store: 64 rows x 35 f32x4 (140 cols contiguous), bias on read
    #pragma unroll 1
    for (int i = tid; i < 64 * 35; i += 512) {
        int lr = i / 35, ch = i - lr * 35;
        f32x4 v  = *(const f32x4*)(Cl + lr * CLP + ch * 4);
        f32x4 bv = *(const f32x4*)(bias + nh2 * 140 + ch * 4);
        *(f32x4*)(logits + (size_t)(rowbase + lr) * NCOLS + nh2 * 140 + ch * 4) = v + bv;
    }
    // loss: 64 rows x 14 heads (this half's heads), logsumexp w/ bias
    #pragma unroll 1
    for (int p = tid; p < 64 * 14; p += 512) {
        int lr = p / 14, h = p - lr * 14;
        const float* x  = Cl + lr * CLP + h * 10;
        const float* bb = bias + nh2 * 140 + h * 10;
        float xv[10];
        #pragma unroll
        for (int j = 0; j < 10; j++) xv[j] = x[j] + bb[j];
        float mx = xv[0];
        #pragma unroll
        for (int j = 1; j < 10; j++) mx = fmaxf(mx, xv[j]);
        float sm = 0.0f;
        #pragma unroll
        for (int j = 0; j < 10; j++) sm += __expf(xv[j] - mx);
        int lab = labels[(size_t)(rowbase + lr) * NHEADS + nh2 * 14 + h];
        float xl = xv[0];
        #pragma unroll
        for (int j = 1; j < 10; j++) xl = (lab == j) ? xv[j] : xl;
        lsum += mx + __logf(sm) - xl;
    }

    #pragma unroll
    for (int off = 32; off > 0; off >>= 1)
        lsum += __shfl_down(lsum, off, 64);
    if (lane == 0) red[wave] = lsum;
    __syncthreads();
    if (tid == 0) {
        float t = red[0] + red[1] + red[2] + red[3]
                + red[4] + red[5] + red[6] + red[7];
        atomicAdd(loss_out, t * LOSS_SCALE);
    }
}

extern "C" void kernel_launch(void* const* d_in, const int* in_sizes, int n_in,
                              void* d_out, int out_size, void* d_ws, size_t ws_size,
                              hipStream_t stream) {
    const float* hidden = (const float*)d_in[0];
    const int* labels   = (const int*)d_in[1];
    const float* W      = (const float*)d_in[2];
    const float* bias   = (const float*)d_in[3];
    float* out = (float*)d_out;
    short* Wswz = (short*)d_ws;   // 589824 bf16 = 1.18 MB

    (void)hipMemsetAsync(d_out, 0, sizeof(float), stream);     // zero loss accumulator
    mvh_swz<<<288, 256, 0, stream>>>(W, Wswz);
    mvh_gemm<<<1024, 512, 0, stream>>>(hidden, Wswz, bias, out + 1, labels, out);
}